// Round 1
// baseline (97.443 us; speedup 1.0000x reference)
//
#include <hip/hip_runtime.h>

constexpr int K = 3;

__global__ __launch_bounds__(256) void deform_conv2d_kernel(
    const float* __restrict__ inp,     // (B,H,W)
    const float* __restrict__ wgt,     // (K*K)
    const float* __restrict__ off,     // (B, 2*K*K, H, W)
    float* __restrict__ out,           // (B,H,W)
    int B, int H, int W)
{
    const int idx = blockIdx.x * blockDim.x + threadIdx.x;  // one thread = 4 pixels
    const int npix4 = (B * H * W) >> 2;
    if (idx >= npix4) return;

    const int p4 = idx << 2;
    const int HW = H * W;
    const int b  = p4 / HW;
    const int hw = p4 - b * HW;
    const int h  = hw / W;
    const int w  = hw - h * W;

    const float* __restrict__ img  = inp + (size_t)b * HW;
    const float* __restrict__ offb = off + (size_t)b * (2 * K * K) * HW + hw;

    // broadcast weights into registers (same address across wave -> cached)
    float wk[K * K];
#pragma unroll
    for (int k = 0; k < K * K; ++k) wk[k] = wgt[k];

    float acc[4] = {0.f, 0.f, 0.f, 0.f};

#pragma unroll
    for (int k = 0; k < K * K; ++k) {
        const int ky = k / K - 1;
        const int kx = k % K - 1;

        const float4 oy4 = *reinterpret_cast<const float4*>(offb + (size_t)(2 * k)     * HW);
        const float4 ox4 = *reinterpret_cast<const float4*>(offb + (size_t)(2 * k + 1) * HW);
        const float oys[4] = {oy4.x, oy4.y, oy4.z, oy4.w};
        const float oxs[4] = {ox4.x, ox4.y, ox4.z, ox4.w};

#pragma unroll
        for (int j = 0; j < 4; ++j) {
            const float y = (float)(h + ky)     + oys[j];
            const float x = (float)(w + j + kx) + oxs[j];

            const float y0f = floorf(y);
            const float x0f = floorf(x);
            const float ly = y - y0f, lx = x - x0f;
            const float hy = 1.f - ly, hx = 1.f - lx;

            const int y0 = (int)y0f, x0 = (int)x0f;
            const int y1 = y0 + 1,   x1 = x0 + 1;

            const bool vy0 = (y0 >= 0) & (y0 < H);
            const bool vy1 = (y1 >= 0) & (y1 < H);
            const bool vx0 = (x0 >= 0) & (x0 < W);
            const bool vx1 = (x1 >= 0) & (x1 < W);

            const float v00 = (vy0 & vx0) ? img[(size_t)y0 * W + x0] : 0.f;
            const float v01 = (vy0 & vx1) ? img[(size_t)y0 * W + x1] : 0.f;
            const float v10 = (vy1 & vx0) ? img[(size_t)y1 * W + x0] : 0.f;
            const float v11 = (vy1 & vx1) ? img[(size_t)y1 * W + x1] : 0.f;

            acc[j] += wk[k] * (hy * hx * v00 + hy * lx * v01 + ly * hx * v10 + ly * lx * v11);
        }
    }

    *reinterpret_cast<float4*>(out + p4) = make_float4(acc[0], acc[1], acc[2], acc[3]);
}

extern "C" void kernel_launch(void* const* d_in, const int* in_sizes, int n_in,
                              void* d_out, int out_size, void* d_ws, size_t ws_size,
                              hipStream_t stream)
{
    const float* inp = (const float*)d_in[0];   // (8,512,512)
    const float* wgt = (const float*)d_in[1];   // (1,1,3,3) = 9 floats
    const float* off = (const float*)d_in[2];   // (8,18,512,512)
    float* out = (float*)d_out;

    const int B = 8, H = 512, W = 512;
    const int npix4 = (B * H * W) / 4;
    const int block = 256;
    const int grid = (npix4 + block - 1) / block;

    deform_conv2d_kernel<<<grid, block, 0, stream>>>(inp, wgt, off, out, B, H, W);
}

// Round 2
// 52.452 us; speedup vs baseline: 1.8578x; 1.8578x over previous
//
#include <hip/hip_runtime.h>

constexpr int K = 3;

__global__ __launch_bounds__(256, 8) void deform_conv2d_kernel(
    const float* __restrict__ inp,     // (B,H,W)
    const float* __restrict__ wgt,     // (K*K)
    const float* __restrict__ off,     // (B, 2*K*K, H, W)
    float* __restrict__ out,           // (B,H,W)
    int B, int H, int W)
{
    const int p = blockIdx.x * blockDim.x + threadIdx.x;  // one thread = 1 pixel
    const int HW = H * W;
    const int npix = B * HW;
    if (p >= npix) return;

    const int b  = p / HW;
    const int hw = p - b * HW;
    const int h  = hw / W;
    const int w  = hw - h * W;

    const float* __restrict__ img  = inp + (size_t)b * HW;
    const float* __restrict__ offb = off + (size_t)b * (2 * K * K) * HW + hw;

    // Issue all 18 offset loads up-front: independent, fully coalesced dwords
    // (consecutive lanes -> consecutive hw within each channel plane).
    float oy[K * K], ox[K * K];
#pragma unroll
    for (int k = 0; k < K * K; ++k) {
        oy[k] = offb[(size_t)(2 * k)     * HW];
        ox[k] = offb[(size_t)(2 * k + 1) * HW];
    }

    float acc = 0.f;

#pragma unroll
    for (int k = 0; k < K * K; ++k) {
        const int ky = k / K - 1;
        const int kx = k % K - 1;

        const float y = (float)(h + ky) + oy[k];
        const float x = (float)(w + kx) + ox[k];

        const float y0f = floorf(y);
        const float x0f = floorf(x);
        const float ly = y - y0f, lx = x - x0f;
        const float hy = 1.f - ly, hx = 1.f - lx;

        const int y0 = (int)y0f, x0 = (int)x0f;
        const int y1 = y0 + 1,   x1 = x0 + 1;

        const bool vy0 = (y0 >= 0) & (y0 < H);
        const bool vy1 = (y1 >= 0) & (y1 < H);
        const bool vx0 = (x0 >= 0) & (x0 < W);
        const bool vx1 = (x1 >= 0) & (x1 < W);

        const float v00 = (vy0 & vx0) ? img[y0 * W + x0] : 0.f;
        const float v01 = (vy0 & vx1) ? img[y0 * W + x1] : 0.f;
        const float v10 = (vy1 & vx0) ? img[y1 * W + x0] : 0.f;
        const float v11 = (vy1 & vx1) ? img[y1 * W + x1] : 0.f;

        // wgt[k]: wave-uniform scalar load (constant index, uniform pointer)
        acc += wgt[k] * (hy * hx * v00 + hy * lx * v01 + ly * hx * v10 + ly * lx * v11);
    }

    out[p] = acc;
}

extern "C" void kernel_launch(void* const* d_in, const int* in_sizes, int n_in,
                              void* d_out, int out_size, void* d_ws, size_t ws_size,
                              hipStream_t stream)
{
    const float* inp = (const float*)d_in[0];   // (8,512,512)
    const float* wgt = (const float*)d_in[1];   // (1,1,3,3) = 9 floats
    const float* off = (const float*)d_in[2];   // (8,18,512,512)
    float* out = (float*)d_out;

    const int B = 8, H = 512, W = 512;
    const int npix = B * H * W;
    const int block = 256;
    const int grid = (npix + block - 1) / block;

    deform_conv2d_kernel<<<grid, block, 0, stream>>>(inp, wgt, off, out, B, H, W);
}